// Round 8
// baseline (1520.359 us; speedup 1.0000x reference)
//
#include <hip/hip_runtime.h>
#include <math.h>

#define BATCH 65536
#define LEAD  24
#define MEM   51
#define NPRED 6
#define HID   128
#define DIN   54      // 2*LEAD + NPRED
#define TB    64      // batch elements per block
#define NBLK  4
#define NKNOT 5
#define OUTC  960     // LEAD * NBLK * 2 * NKNOT

__device__ __forceinline__ float sp_softplus(float z) {
    return fmaxf(z, 0.0f) + log1pf(expf(-fabsf(z)));
}
__device__ __forceinline__ float silu_f(float z) {
    return z / (1.0f + expf(-z));
}

// Weight fetches go through the VECTOR memory path (not s_load/scalar cache):
// an opaque VGPR zero is added to the address so the compiler cannot prove
// wave-uniformity. Rationale: scalar cache is 16 KB/CU vs 64 KB weight layer
// × 15 concurrent waves -> sK$ thrash, every s_load ~L2 latency, serialized
// by lgkmcnt (rounds 2/6/7: VALUBusy pinned at 44-48% regardless of occupancy).
// Vector loads broadcast (all lanes same addr) and pipeline deep via vmcnt.
__global__ __launch_bounds__(256, 4) void fused_pdf_kernel(
    const float* __restrict__ x, const float* __restrict__ p, const float* __restrict__ f,
    const float* __restrict__ W_in, const float* __restrict__ b_in,
    const float* __restrict__ Ws0, const float* __restrict__ bs0,
    const float* __restrict__ Ws1, const float* __restrict__ bs1,
    const float* __restrict__ Ws2, const float* __restrict__ bs2,
    const float* __restrict__ Ws3, const float* __restrict__ bs3,
    const float* __restrict__ W_out, const float* __restrict__ b_out,
    float* __restrict__ out)
{
    __shared__ float s_buf[HID * TB];  // 32 KB, time-shared input/hidden tile

    const int t    = threadIdx.x;
    const int lane = t & 63;
    const int w    = t >> 6;
    const int b0   = blockIdx.x * TB;

    // opaque zero in a VGPR — compiler must treat as divergent
    int vzero;
    asm volatile("v_mov_b32 %0, 0" : "=v"(vzero));

    // ---------------- phase 0: per-(b,lead) mean/std over 51 members ----------------
    {
        const int grp = lane >> 4, sub = lane & 15;
        for (int it = 0; it < (TB * LEAD) / 16; ++it) {
            int rowl = it * 16 + w * 4 + grp;
            const float* xr = x + (size_t)(b0 * LEAD + rowl) * MEM;
            float v0 = xr[sub], v1 = xr[sub + 16], v2 = xr[sub + 32];
            float v3 = (sub < 3) ? xr[sub + 48] : 0.0f;
            float sum = v0 + v1 + v2 + v3;
            float ss  = v0 * v0 + v1 * v1 + v2 * v2 + v3 * v3;
            sum += __shfl_xor(sum, 1);  ss += __shfl_xor(ss, 1);
            sum += __shfl_xor(sum, 2);  ss += __shfl_xor(ss, 2);
            sum += __shfl_xor(sum, 4);  ss += __shfl_xor(ss, 4);
            sum += __shfl_xor(sum, 8);  ss += __shfl_xor(ss, 8);
            if (sub == 0) {
                int bl = rowl / LEAD, ld = rowl - bl * LEAD;
                float m   = sum / 51.0f;
                float var = (ss - 51.0f * m * m) / 50.0f;
                s_buf[(2 * ld) * TB + bl]     = m;
                s_buf[(2 * ld + 1) * TB + bl] = sqrtf(fmaxf(var, 0.0f));
            }
        }
        for (int idx = t; idx < TB * NPRED; idx += 256) {
            int bl = idx / NPRED, j = idx - bl * NPRED;
            s_buf[(2 * LEAD + j) * TB + bl] = p[(size_t)(b0 + bl) * NPRED + j];
        }
    }
    __syncthreads();

    const int j0 = __builtin_amdgcn_readfirstlane(w * 32);

    float hreg[32];

    // ---------------- phase 1: input layer [54 -> 128], silu ----------------
    {
        float acc[32];
        #pragma unroll
        for (int jj = 0; jj < 32; ++jj) acc[jj] = 0.0f;
        for (int k = 0; k < DIN; ++k) {
            float a = s_buf[k * TB + lane];
            const float4* wp4 = (const float4*)(W_in + vzero + k * HID + j0);
            #pragma unroll
            for (int v = 0; v < 8; ++v) {
                float4 wv = wp4[v];
                acc[4 * v + 0] = fmaf(a, wv.x, acc[4 * v + 0]);
                acc[4 * v + 1] = fmaf(a, wv.y, acc[4 * v + 1]);
                acc[4 * v + 2] = fmaf(a, wv.z, acc[4 * v + 2]);
                acc[4 * v + 3] = fmaf(a, wv.w, acc[4 * v + 3]);
            }
        }
        __syncthreads();
        #pragma unroll
        for (int jj = 0; jj < 32; ++jj) {
            hreg[jj] = silu_f(acc[jj] + b_in[j0 + jj]);
            s_buf[(j0 + jj) * TB + lane] = hreg[jj];
        }
    }
    __syncthreads();

    // ---------------- phase 2: 4 skip blocks: h = silu(h@W+b) + h ----------------
    const float* Wl[4] = {Ws0, Ws1, Ws2, Ws3};
    const float* Bl[4] = {bs0, bs1, bs2, bs3};
    #pragma unroll
    for (int L = 0; L < 4; ++L) {
        const float* Wp = Wl[L];
        const float* bp = Bl[L];
        float acc[32];
        #pragma unroll
        for (int jj = 0; jj < 32; ++jj) acc[jj] = 0.0f;
        for (int k = 0; k < HID; ++k) {
            float a = s_buf[k * TB + lane];
            const float4* wp4 = (const float4*)(Wp + vzero + k * HID + j0);
            #pragma unroll
            for (int v = 0; v < 8; ++v) {
                float4 wv = wp4[v];
                acc[4 * v + 0] = fmaf(a, wv.x, acc[4 * v + 0]);
                acc[4 * v + 1] = fmaf(a, wv.y, acc[4 * v + 1]);
                acc[4 * v + 2] = fmaf(a, wv.z, acc[4 * v + 2]);
                acc[4 * v + 3] = fmaf(a, wv.w, acc[4 * v + 3]);
            }
        }
        __syncthreads();
        #pragma unroll
        for (int jj = 0; jj < 32; ++jj) {
            hreg[jj] = silu_f(acc[jj] + bp[j0 + jj]) + hreg[jj];
            s_buf[(j0 + jj) * TB + lane] = hreg[jj];
        }
        __syncthreads();
    }

    // ---------------- phase 3+4: output cols per lead + spline flow ----------------
    for (int q = 0; q < LEAD / 4; ++q) {
        const int lead = __builtin_amdgcn_readfirstlane(q * 4 + w);
        const int base = lead * 40;

        float acc[40];
        #pragma unroll
        for (int c = 0; c < 40; ++c) acc[c] = 0.0f;
        for (int k = 0; k < HID; ++k) {
            float a = s_buf[k * TB + lane];
            const float4* wp4 = (const float4*)(W_out + vzero + k * OUTC + base);
            #pragma unroll
            for (int v = 0; v < 10; ++v) {
                float4 wv = wp4[v];
                acc[4 * v + 0] = fmaf(a, wv.x, acc[4 * v + 0]);
                acc[4 * v + 1] = fmaf(a, wv.y, acc[4 * v + 1]);
                acc[4 * v + 2] = fmaf(a, wv.z, acc[4 * v + 2]);
                acc[4 * v + 3] = fmaf(a, wv.w, acc[4 * v + 3]);
            }
        }
        #pragma unroll
        for (int c = 0; c < 40; ++c) acc[c] += b_out[base + c];

        float ff = f[(size_t)(b0 + lane) * LEAD + lead];
        float dt_prod = 1.0f;

        #pragma unroll
        for (int blk = 0; blk < NBLK; ++blk) {
            float tk[5], yk[5];
            tk[0] = acc[blk * 10 + 0];
            yk[0] = acc[blk * 10 + 5];
            #pragma unroll
            for (int kk = 1; kk < 5; ++kk) {
                tk[kk] = tk[kk - 1] + 0.001f + sp_softplus(acc[blk * 10 + kk]);
                yk[kk] = yk[kk - 1] + 0.001f + sp_softplus(acc[blk * 10 + 5 + kk]);
            }
            float df[4];
            #pragma unroll
            for (int j = 0; j < 4; ++j) df[j] = (yk[j + 1] - yk[j]) / (tk[j + 1] - tk[j]);
            float g02 = (yk[2] - yk[0]) / (tk[2] - tk[0]);
            float g13 = (yk[3] - yk[1]) / (tk[3] - tk[1]);
            float g24 = (yk[4] - yk[2]) / (tk[4] - tk[2]);
            float dd[5];
            dd[0] = df[0] * df[0] / g02;
            dd[1] = df[0] * df[1] / g02;
            dd[2] = df[1] * df[2] / g13;
            dd[3] = df[2] * df[3] / g24;
            dd[4] = df[3] * df[3] / g24;

            int cnt = (ff > tk[0]) + (ff > tk[1]) + (ff > tk[2]) + (ff > tk[3]) + (ff > tk[4]);
            bool e0 = (cnt == 0), e1 = (cnt == 5);
            int k0 = cnt - 1; k0 = k0 < 0 ? 0 : (k0 > 3 ? 3 : k0);

            float t0v = tk[0], t1v = tk[1], y0v = yk[0], y1v = yk[1], d0v = dd[0], d1v = dd[1];
            #pragma unroll
            for (int j = 1; j < 4; ++j) {
                bool c = (k0 == j);
                t0v = c ? tk[j] : t0v;  t1v = c ? tk[j + 1] : t1v;
                y0v = c ? yk[j] : y0v;  y1v = c ? yk[j + 1] : y1v;
                d0v = c ? dd[j] : d0v;  d1v = c ? dd[j + 1] : d1v;
            }

            float dt_ = t1v - t0v, dy_ = y1v - y0v;
            float s_  = dy_ / dt_;
            float e   = (ff - t0v) / dt_;
            float one_e = 1.0f - e;
            float bb  = d1v + d0v - 2.0f * s_;
            float n0  = dy_ * (s_ * e * e + d0v * e * one_e);
            float n1  = s_ + bb * e * one_e;
            float p_mid = y0v + n0 / n1;
            float p_lo  = d0v * ff + (y0v - d0v * t0v);
            float p_hi  = d1v * ff + (y1v - d1v * t1v);
            float val = e0 ? p_lo : (e1 ? p_hi : p_mid);

            float div0 = s_ * s_ * (d1v * e * e + 2.0f * s_ * e * one_e + d0v * one_e * one_e);
            float div1 = n1 * n1;
            float der  = e0 ? d0v : (e1 ? d1v : div0 / div1);

            dt_prod *= der;
            ff = val;
        }

        out[(size_t)(b0 + lane) * LEAD + lead] =
            expf(-0.5f * ff * ff) * dt_prod / 2.5066282746310002f;
    }
}

extern "C" void kernel_launch(void* const* d_in, const int* in_sizes, int n_in,
                              void* d_out, int out_size, void* d_ws, size_t ws_size,
                              hipStream_t stream) {
    const float* x     = (const float*)d_in[0];
    const float* p     = (const float*)d_in[1];
    const float* f     = (const float*)d_in[2];
    const float* W_in  = (const float*)d_in[3];
    const float* b_in  = (const float*)d_in[4];
    const float* Ws0   = (const float*)d_in[5];
    const float* bs0   = (const float*)d_in[6];
    const float* Ws1   = (const float*)d_in[7];
    const float* bs1   = (const float*)d_in[8];
    const float* Ws2   = (const float*)d_in[9];
    const float* bs2   = (const float*)d_in[10];
    const float* Ws3   = (const float*)d_in[11];
    const float* bs3   = (const float*)d_in[12];
    const float* W_out = (const float*)d_in[13];
    const float* b_out = (const float*)d_in[14];
    float* out = (float*)d_out;

    dim3 grid(BATCH / TB), block(256);
    fused_pdf_kernel<<<grid, block, 0, stream>>>(
        x, p, f, W_in, b_in, Ws0, bs0, Ws1, bs1, Ws2, bs2, Ws3, bs3, W_out, b_out, out);
}

// Round 10
// 554.145 us; speedup vs baseline: 2.7436x; 2.7436x over previous
//
#include <hip/hip_runtime.h>
#include <math.h>

#define BATCH 65536
#define LEAD  24
#define MEM   51
#define NPRED 6
#define HID   128
#define TB    64
#define NBLK  4
#define OUTC  960

#define HSTR  136            // bf16 plane stride (16B-aligned rows; row stride ≡4 mod 32 banks -> uniform per-bank load)
#define HPL   (64 * HSTR)    // elements per plane
#define CSTR  165            // f32 C-stage stride; 165≡5 mod 32, gcd(5,32)=1 -> spline reads 2-way (free); 164 was 8-way

// prepped-weight layout in d_ws (ushort units):
//   W_inT  hi [0,8192)        lo [8192,16384)        ([128][64], k>=54 zero)
//   WsT l  hi 16384+l*32768   lo +16384              ([128][128])
//   W_outT hi 147456          lo 270336              ([960][128])
#define WS_USHORTS 393216
#define WS_BYTES   786432

typedef float f32x4 __attribute__((ext_vector_type(4)));
typedef short s16x8 __attribute__((ext_vector_type(8)));

__device__ __forceinline__ float sp_softplus(float z) {
    return fmaxf(z, 0.0f) + log1pf(expf(-fabsf(z)));
}
__device__ __forceinline__ float silu_f(float z) {
    return z / (1.0f + expf(-z));
}
// x ~= hi + lo (bf16 each), dropped term <= 2^-16 rel
__device__ __forceinline__ void bf16split(float x, unsigned &hi, unsigned &lo) {
    unsigned xb = __float_as_uint(x);
    hi = xb >> 16;
    float fhi = __uint_as_float(xb & 0xFFFF0000u);
    lo = __float_as_uint(x - fhi) >> 16;
}
__device__ __forceinline__ float bf16re(short u) {
    return __uint_as_float(((unsigned)(unsigned short)u) << 16);
}

// ---------------- prep: transpose + hi/lo split all weights into d_ws ----------------
__global__ __launch_bounds__(256) void prep_kernel(
    const float* __restrict__ W_in,
    const float* __restrict__ Ws0, const float* __restrict__ Ws1,
    const float* __restrict__ Ws2, const float* __restrict__ Ws3,
    const float* __restrict__ W_out, unsigned short* __restrict__ wq)
{
    int idx = blockIdx.x * 256 + threadIdx.x;   // 0..196607
    float val; int ih, il;
    if (idx < 8192) {                  // W_inT [n][k], K padded 54->64
        int n = idx >> 6, k = idx & 63;
        val = (k < 54) ? W_in[k * HID + n] : 0.0f;
        ih = idx; il = 8192 + idx;
    } else if (idx < 73728) {          // WsT
        int r = idx - 8192, l = r >> 14, r2 = r & 16383;
        int n = r2 >> 7, k = r2 & 127;
        const float* W = (l == 0) ? Ws0 : (l == 1) ? Ws1 : (l == 2) ? Ws2 : Ws3;
        val = W[k * HID + n];
        ih = 16384 + l * 32768 + r2; il = ih + 16384;
    } else {                           // W_outT
        int r = idx - 73728;
        int n = r >> 7, k = r & 127;
        val = W_out[k * OUTC + n];
        ih = 147456 + r; il = 270336 + r;
    }
    unsigned hi, lo; bf16split(val, hi, lo);
    wq[ih] = (unsigned short)hi;
    wq[il] = (unsigned short)lo;
}

// ---------------- writeback: acc -> silu(+skip) -> split bf16 planes ----------------
template<bool SKIP>
__device__ __forceinline__ void writeback(f32x4 (&acc)[4][2], short* hpl,
                                          const float* __restrict__ bias,
                                          int w, int lL, int lH) {
    const bool evn = (lL & 1) == 0;
    unsigned* u32p = (unsigned*)hpl;
    #pragma unroll
    for (int n = 0; n < 2; ++n) {
        const int colb = w * 32 + n * 16 + lL;
        const float bv = bias[colb];
        #pragma unroll
        for (int m = 0; m < 4; ++m) {
            #pragma unroll
            for (int r = 0; r < 4; ++r) {
                const int row = m * 16 + lH * 4 + r;
                float v = acc[m][n][r] + bv;
                float hnew;
                if (SKIP) {
                    float ho = bf16re(hpl[row * HSTR + colb]) + bf16re(hpl[HPL + row * HSTR + colb]);
                    hnew = silu_f(v) + ho;   // ds_read precedes ds_write in program order: safe
                } else {
                    hnew = silu_f(v);
                }
                unsigned hi, lo; bf16split(hnew, hi, lo);
                unsigned phi = (unsigned)__shfl_xor((int)hi, 1);
                unsigned plo = (unsigned)__shfl_xor((int)lo, 1);
                if (evn) {   // even-col lane packs (col, col+1) -> one b32 per plane
                    u32p[(row * HSTR + colb) >> 1]       = hi | (phi << 16);
                    u32p[(HPL + row * HSTR + colb) >> 1] = lo | (plo << 16);
                }
            }
        }
    }
}

#define MFMA(a, b, c) __builtin_amdgcn_mfma_f32_16x16x32_bf16((a), (b), (c), 0, 0, 0)

// ---------------- main fused kernel (MFMA path) ----------------
__global__ __launch_bounds__(256, 2) void fused_mfma_kernel(
    const float* __restrict__ x, const float* __restrict__ p, const float* __restrict__ f,
    const float* __restrict__ b_in,
    const float* __restrict__ bs0, const float* __restrict__ bs1,
    const float* __restrict__ bs2, const float* __restrict__ bs3,
    const float* __restrict__ b_out,
    const unsigned short* __restrict__ wq,
    float* __restrict__ out)
{
    __shared__ short hpl[2 * HPL];        // 34816 B: activation hi/lo planes [64][HSTR]
    __shared__ float cbuf[64 * CSTR];     // 42240 B: out-layer C stage (4 leads = 160 cols)

    const int t    = threadIdx.x;
    const int lane = t & 63;
    const int w    = t >> 6;
    const int lL   = lane & 15;
    const int lH   = lane >> 4;
    const int b0   = blockIdx.x * TB;

    // -------- phase 0: stats -> split-bf16 input planes (cols 0..53, 54..63 zero) --------
    {
        const int grp = lane >> 4, sub = lane & 15;
        for (int it = 0; it < (TB * LEAD) / 16; ++it) {
            int rowl = it * 16 + w * 4 + grp;
            const float* xr = x + (size_t)(b0 * LEAD + rowl) * MEM;
            float v0 = xr[sub], v1 = xr[sub + 16], v2 = xr[sub + 32];
            float v3 = (sub < 3) ? xr[sub + 48] : 0.0f;
            float sum = v0 + v1 + v2 + v3;
            float ss  = v0 * v0 + v1 * v1 + v2 * v2 + v3 * v3;
            sum += __shfl_xor(sum, 1);  ss += __shfl_xor(ss, 1);
            sum += __shfl_xor(sum, 2);  ss += __shfl_xor(ss, 2);
            sum += __shfl_xor(sum, 4);  ss += __shfl_xor(ss, 4);
            sum += __shfl_xor(sum, 8);  ss += __shfl_xor(ss, 8);
            if (sub == 0) {
                int bl = rowl / LEAD, ld = rowl - bl * LEAD;
                float mv = sum / 51.0f;
                float sd = sqrtf(fmaxf((ss - 51.0f * mv * mv) / 50.0f, 0.0f));
                unsigned hi, lo;
                bf16split(mv, hi, lo);
                hpl[bl * HSTR + 2 * ld] = (short)hi;  hpl[HPL + bl * HSTR + 2 * ld] = (short)lo;
                bf16split(sd, hi, lo);
                hpl[bl * HSTR + 2 * ld + 1] = (short)hi;  hpl[HPL + bl * HSTR + 2 * ld + 1] = (short)lo;
            }
        }
        for (int idx = t; idx < TB * NPRED; idx += 256) {
            int bl = idx / NPRED, j = idx - bl * NPRED;
            unsigned hi, lo;
            bf16split(p[(size_t)(b0 + bl) * NPRED + j], hi, lo);
            hpl[bl * HSTR + 48 + j] = (short)hi;  hpl[HPL + bl * HSTR + 48 + j] = (short)lo;
        }
        {   // zero-pad cols 54..63
            int row = t >> 2;
            unsigned* u32p = (unsigned*)hpl;
            for (int c2 = 54 + 2 * (t & 3); c2 < 64; c2 += 8) {
                u32p[(row * HSTR + c2) >> 1] = 0u;
                u32p[(HPL + row * HSTR + c2) >> 1] = 0u;
            }
        }
    }
    __syncthreads();

    // -------- phase 1: input layer GEMM 64x128, K=64, 3-pass split --------
    {
        f32x4 acc[4][2];
        #pragma unroll
        for (int m = 0; m < 4; ++m)
            #pragma unroll
            for (int n = 0; n < 2; ++n) acc[m][n] = (f32x4){0.f, 0.f, 0.f, 0.f};
        #pragma unroll
        for (int n = 0; n < 2; ++n) {
            const int colg = w * 32 + n * 16 + lL;
            #pragma unroll
            for (int kk = 0; kk < 2; ++kk) {
                s16x8 bh = *(const s16x8*)(wq + colg * 64 + kk * 32 + lH * 8);
                s16x8 bl = *(const s16x8*)(wq + 8192 + colg * 64 + kk * 32 + lH * 8);
                #pragma unroll
                for (int m = 0; m < 4; ++m) {
                    const short* ap = &hpl[(m * 16 + lL) * HSTR + kk * 32 + lH * 8];
                    s16x8 ah = *(const s16x8*)ap;
                    s16x8 al = *(const s16x8*)(ap + HPL);
                    acc[m][n] = MFMA(ah, bh, acc[m][n]);
                    acc[m][n] = MFMA(ah, bl, acc[m][n]);
                    acc[m][n] = MFMA(al, bh, acc[m][n]);
                }
            }
        }
        __syncthreads();
        writeback<false>(acc, hpl, b_in, w, lL, lH);
    }
    __syncthreads();

    // -------- phase 2: 4 skip layers, K=128 --------
    {
        const float* bsp[4] = {bs0, bs1, bs2, bs3};
        #pragma unroll 1
        for (int L = 0; L < 4; ++L) {
            const unsigned short* wsl = wq + 16384 + L * 32768;
            const float* bp = bsp[L];
            f32x4 acc[4][2];
            #pragma unroll
            for (int m = 0; m < 4; ++m)
                #pragma unroll
                for (int n = 0; n < 2; ++n) acc[m][n] = (f32x4){0.f, 0.f, 0.f, 0.f};
            #pragma unroll
            for (int n = 0; n < 2; ++n) {
                const int colg = w * 32 + n * 16 + lL;
                #pragma unroll
                for (int kk = 0; kk < 4; ++kk) {
                    s16x8 bh = *(const s16x8*)(wsl + colg * 128 + kk * 32 + lH * 8);
                    s16x8 bl = *(const s16x8*)(wsl + 16384 + colg * 128 + kk * 32 + lH * 8);
                    #pragma unroll
                    for (int m = 0; m < 4; ++m) {
                        const short* ap = &hpl[(m * 16 + lL) * HSTR + kk * 32 + lH * 8];
                        s16x8 ah = *(const s16x8*)ap;
                        s16x8 al = *(const s16x8*)(ap + HPL);
                        acc[m][n] = MFMA(ah, bh, acc[m][n]);
                        acc[m][n] = MFMA(ah, bl, acc[m][n]);
                        acc[m][n] = MFMA(al, bh, acc[m][n]);
                    }
                }
            }
            __syncthreads();
            writeback<true>(acc, hpl, bp, w, lL, lH);
            __syncthreads();
        }
    }

    // -------- phase 3: out layer (4 leads/group, waves split M) + spline --------
    const unsigned short* wop = wq + 147456;
    #pragma unroll 1
    for (int g = 0; g < 6; ++g) {
        #pragma unroll 1
        for (int nt = 0; nt < 10; ++nt) {
            const int colg = g * 160 + nt * 16 + lL;
            f32x4 d = {0.f, 0.f, 0.f, 0.f};
            #pragma unroll
            for (int kk = 0; kk < 4; ++kk) {
                s16x8 bh = *(const s16x8*)(wop + colg * 128 + kk * 32 + lH * 8);
                s16x8 bl = *(const s16x8*)(wop + 122880 + colg * 128 + kk * 32 + lH * 8);
                const short* ap = &hpl[(w * 16 + lL) * HSTR + kk * 32 + lH * 8];
                s16x8 ah = *(const s16x8*)ap;
                s16x8 al = *(const s16x8*)(ap + HPL);
                d = MFMA(ah, bh, d);
                d = MFMA(ah, bl, d);
                d = MFMA(al, bh, d);
            }
            const float bv = b_out[colg];
            #pragma unroll
            for (int r = 0; r < 4; ++r)
                cbuf[(w * 16 + lH * 4 + r) * CSTR + nt * 16 + lL] = d[r] + bv;
        }
        __syncthreads();

        {   // spline: thread -> (b = t&63, lead = g*4 + (t>>6))
            const int b = t & 63, l = t >> 6;
            const float* cc = &cbuf[b * CSTR + l * 40];
            float ff = f[(size_t)(b0 + b) * LEAD + g * 4 + l];
            float dt_prod = 1.0f;
            #pragma unroll
            for (int blk = 0; blk < NBLK; ++blk) {
                float tk[5], yk[5];
                tk[0] = cc[blk * 10 + 0];
                yk[0] = cc[blk * 10 + 5];
                #pragma unroll
                for (int kk = 1; kk < 5; ++kk) {
                    tk[kk] = tk[kk - 1] + 0.001f + sp_softplus(cc[blk * 10 + kk]);
                    yk[kk] = yk[kk - 1] + 0.001f + sp_softplus(cc[blk * 10 + 5 + kk]);
                }
                float df[4];
                #pragma unroll
                for (int j = 0; j < 4; ++j) df[j] = (yk[j + 1] - yk[j]) / (tk[j + 1] - tk[j]);
                float g02 = (yk[2] - yk[0]) / (tk[2] - tk[0]);
                float g13 = (yk[3] - yk[1]) / (tk[3] - tk[1]);
                float g24 = (yk[4] - yk[2]) / (tk[4] - tk[2]);
                float dd[5];
                dd[0] = df[0] * df[0] / g02;
                dd[1] = df[0] * df[1] / g02;
                dd[2] = df[1] * df[2] / g13;
                dd[3] = df[2] * df[3] / g24;
                dd[4] = df[3] * df[3] / g24;

                int cnt = (ff > tk[0]) + (ff > tk[1]) + (ff > tk[2]) + (ff > tk[3]) + (ff > tk[4]);
                bool e0 = (cnt == 0), e1 = (cnt == 5);
                int k0 = cnt - 1; k0 = k0 < 0 ? 0 : (k0 > 3 ? 3 : k0);

                float t0v = tk[0], t1v = tk[1], y0v = yk[0], y1v = yk[1], d0v = dd[0], d1v = dd[1];
                #pragma unroll
                for (int j = 1; j < 4; ++j) {
                    bool c = (k0 == j);
                    t0v = c ? tk[j] : t0v;  t1v = c ? tk[j + 1] : t1v;
                    y0v = c ? yk[j] : y0v;  y1v = c ? yk[j + 1] : y1v;
                    d0v = c ? dd[j] : d0v;  d1v = c ? dd[j + 1] : d1v;
                }

                float dt_ = t1v - t0v, dy_ = y1v - y0v;
                float s_  = dy_ / dt_;
                float e   = (ff - t0v) / dt_;
                float one_e = 1.0f - e;
                float bb  = d1v + d0v - 2.0f * s_;
                float n0  = dy_ * (s_ * e * e + d0v * e * one_e);
                float n1  = s_ + bb * e * one_e;
                float p_mid = y0v + n0 / n1;
                float p_lo  = d0v * ff + (y0v - d0v * t0v);
                float p_hi  = d1v * ff + (y1v - d1v * t1v);
                float val = e0 ? p_lo : (e1 ? p_hi : p_mid);

                float div0 = s_ * s_ * (d1v * e * e + 2.0f * s_ * e * one_e + d0v * one_e * one_e);
                float div1 = n1 * n1;
                float der  = e0 ? d0v : (e1 ? d1v : div0 / div1);

                dt_prod *= der;
                ff = val;
            }
            out[(size_t)(b0 + b) * LEAD + g * 4 + l] =
                expf(-0.5f * ff * ff) * dt_prod / 2.5066282746310002f;
        }
        __syncthreads();
    }
}

// ---------------- legacy fallback (round-2 kernel, used only if ws too small) ----------------
#define DIN 54
__global__ __launch_bounds__(256, 2) void fused_pdf_legacy(
    const float* __restrict__ x, const float* __restrict__ p, const float* __restrict__ f,
    const float* __restrict__ W_in, const float* __restrict__ b_in,
    const float* __restrict__ Ws0, const float* __restrict__ bs0,
    const float* __restrict__ Ws1, const float* __restrict__ bs1,
    const float* __restrict__ Ws2, const float* __restrict__ bs2,
    const float* __restrict__ Ws3, const float* __restrict__ bs3,
    const float* __restrict__ W_out, const float* __restrict__ b_out,
    float* __restrict__ out)
{
    __shared__ float s_in[DIN * TB];
    __shared__ float s_h[HID * TB];
    const int t = threadIdx.x, lane = t & 63, w = t >> 6;
    const int b0 = blockIdx.x * TB;
    {
        const int grp = lane >> 4, sub = lane & 15;
        for (int it = 0; it < (TB * LEAD) / 16; ++it) {
            int rowl = it * 16 + w * 4 + grp;
            const float* xr = x + (size_t)(b0 * LEAD + rowl) * MEM;
            float v0 = xr[sub], v1 = xr[sub + 16], v2 = xr[sub + 32];
            float v3 = (sub < 3) ? xr[sub + 48] : 0.0f;
            float sum = v0 + v1 + v2 + v3;
            float ss  = v0 * v0 + v1 * v1 + v2 * v2 + v3 * v3;
            sum += __shfl_xor(sum, 1);  ss += __shfl_xor(ss, 1);
            sum += __shfl_xor(sum, 2);  ss += __shfl_xor(ss, 2);
            sum += __shfl_xor(sum, 4);  ss += __shfl_xor(ss, 4);
            sum += __shfl_xor(sum, 8);  ss += __shfl_xor(ss, 8);
            if (sub == 0) {
                int bl = rowl / LEAD, ld = rowl - bl * LEAD;
                float m = sum / 51.0f;
                float var = (ss - 51.0f * m * m) / 50.0f;
                s_in[(2 * ld) * TB + bl] = m;
                s_in[(2 * ld + 1) * TB + bl] = sqrtf(fmaxf(var, 0.0f));
            }
        }
        for (int idx = t; idx < TB * NPRED; idx += 256) {
            int bl = idx / NPRED, j = idx - bl * NPRED;
            s_in[(2 * LEAD + j) * TB + bl] = p[(size_t)(b0 + bl) * NPRED + j];
        }
    }
    __syncthreads();
    const int j0 = __builtin_amdgcn_readfirstlane(w * 32);
    float hreg[32];
    {
        float acc[32];
        #pragma unroll
        for (int jj = 0; jj < 32; ++jj) acc[jj] = 0.0f;
        for (int k = 0; k < DIN; ++k) {
            float a = s_in[k * TB + lane];
            const float* wr = W_in + k * HID + j0;
            #pragma unroll
            for (int jj = 0; jj < 32; ++jj) acc[jj] = fmaf(a, wr[jj], acc[jj]);
        }
        #pragma unroll
        for (int jj = 0; jj < 32; ++jj) {
            hreg[jj] = silu_f(acc[jj] + b_in[j0 + jj]);
            s_h[(j0 + jj) * TB + lane] = hreg[jj];
        }
    }
    __syncthreads();
    const float* Wl[4] = {Ws0, Ws1, Ws2, Ws3};
    const float* Bl[4] = {bs0, bs1, bs2, bs3};
    #pragma unroll
    for (int L = 0; L < 4; ++L) {
        const float* Wp = Wl[L];
        const float* bp = Bl[L];
        float acc[32];
        #pragma unroll
        for (int jj = 0; jj < 32; ++jj) acc[jj] = 0.0f;
        for (int k = 0; k < HID; ++k) {
            float a = s_h[k * TB + lane];
            const float* wr = Wp + k * HID + j0;
            #pragma unroll
            for (int jj = 0; jj < 32; ++jj) acc[jj] = fmaf(a, wr[jj], acc[jj]);
        }
        __syncthreads();
        #pragma unroll
        for (int jj = 0; jj < 32; ++jj) {
            hreg[jj] = silu_f(acc[jj] + bp[j0 + jj]) + hreg[jj];
            s_h[(j0 + jj) * TB + lane] = hreg[jj];
        }
        __syncthreads();
    }
    for (int q = 0; q < LEAD / 4; ++q) {
        const int lead = __builtin_amdgcn_readfirstlane(q * 4 + w);
        const int base = lead * 40;
        float acc[40];
        #pragma unroll
        for (int c = 0; c < 40; ++c) acc[c] = 0.0f;
        for (int k = 0; k < HID; ++k) {
            float a = s_h[k * TB + lane];
            const float* wr = W_out + k * OUTC + base;
            #pragma unroll
            for (int c = 0; c < 40; ++c) acc[c] = fmaf(a, wr[c], acc[c]);
        }
        #pragma unroll
        for (int c = 0; c < 40; ++c) acc[c] += b_out[base + c];
        float ff = f[(size_t)(b0 + lane) * LEAD + lead];
        float dt_prod = 1.0f;
        #pragma unroll
        for (int blk = 0; blk < NBLK; ++blk) {
            float tk[5], yk[5];
            tk[0] = acc[blk * 10 + 0];
            yk[0] = acc[blk * 10 + 5];
            #pragma unroll
            for (int kk = 1; kk < 5; ++kk) {
                tk[kk] = tk[kk - 1] + 0.001f + sp_softplus(acc[blk * 10 + kk]);
                yk[kk] = yk[kk - 1] + 0.001f + sp_softplus(acc[blk * 10 + 5 + kk]);
            }
            float df[4];
            #pragma unroll
            for (int j = 0; j < 4; ++j) df[j] = (yk[j + 1] - yk[j]) / (tk[j + 1] - tk[j]);
            float g02 = (yk[2] - yk[0]) / (tk[2] - tk[0]);
            float g13 = (yk[3] - yk[1]) / (tk[3] - tk[1]);
            float g24 = (yk[4] - yk[2]) / (tk[4] - tk[2]);
            float dd[5];
            dd[0] = df[0] * df[0] / g02;
            dd[1] = df[0] * df[1] / g02;
            dd[2] = df[1] * df[2] / g13;
            dd[3] = df[2] * df[3] / g24;
            dd[4] = df[3] * df[3] / g24;
            int cnt = (ff > tk[0]) + (ff > tk[1]) + (ff > tk[2]) + (ff > tk[3]) + (ff > tk[4]);
            bool e0 = (cnt == 0), e1 = (cnt == 5);
            int k0 = cnt - 1; k0 = k0 < 0 ? 0 : (k0 > 3 ? 3 : k0);
            float t0v = tk[0], t1v = tk[1], y0v = yk[0], y1v = yk[1], d0v = dd[0], d1v = dd[1];
            #pragma unroll
            for (int j = 1; j < 4; ++j) {
                bool c = (k0 == j);
                t0v = c ? tk[j] : t0v;  t1v = c ? tk[j + 1] : t1v;
                y0v = c ? yk[j] : y0v;  y1v = c ? yk[j + 1] : y1v;
                d0v = c ? dd[j] : d0v;  d1v = c ? dd[j + 1] : d1v;
            }
            float dt_ = t1v - t0v, dy_ = y1v - y0v;
            float s_  = dy_ / dt_;
            float e   = (ff - t0v) / dt_;
            float one_e = 1.0f - e;
            float bb  = d1v + d0v - 2.0f * s_;
            float n0  = dy_ * (s_ * e * e + d0v * e * one_e);
            float n1  = s_ + bb * e * one_e;
            float p_mid = y0v + n0 / n1;
            float p_lo  = d0v * ff + (y0v - d0v * t0v);
            float p_hi  = d1v * ff + (y1v - d1v * t1v);
            float val = e0 ? p_lo : (e1 ? p_hi : p_mid);
            float div0 = s_ * s_ * (d1v * e * e + 2.0f * s_ * e * one_e + d0v * one_e * one_e);
            float div1 = n1 * n1;
            float der  = e0 ? d0v : (e1 ? d1v : div0 / div1);
            dt_prod *= der;
            ff = val;
        }
        out[(size_t)(b0 + lane) * LEAD + lead] =
            expf(-0.5f * ff * ff) * dt_prod / 2.5066282746310002f;
    }
}

extern "C" void kernel_launch(void* const* d_in, const int* in_sizes, int n_in,
                              void* d_out, int out_size, void* d_ws, size_t ws_size,
                              hipStream_t stream) {
    const float* x     = (const float*)d_in[0];
    const float* p     = (const float*)d_in[1];
    const float* f     = (const float*)d_in[2];
    const float* W_in  = (const float*)d_in[3];
    const float* b_in  = (const float*)d_in[4];
    const float* Ws0   = (const float*)d_in[5];
    const float* bs0   = (const float*)d_in[6];
    const float* Ws1   = (const float*)d_in[7];
    const float* bs1   = (const float*)d_in[8];
    const float* Ws2   = (const float*)d_in[9];
    const float* bs2   = (const float*)d_in[10];
    const float* Ws3   = (const float*)d_in[11];
    const float* bs3   = (const float*)d_in[12];
    const float* W_out = (const float*)d_in[13];
    const float* b_out = (const float*)d_in[14];
    float* out = (float*)d_out;

    if (ws_size >= (size_t)WS_BYTES) {
        unsigned short* wq = (unsigned short*)d_ws;
        prep_kernel<<<768, 256, 0, stream>>>(W_in, Ws0, Ws1, Ws2, Ws3, W_out, wq);
        fused_mfma_kernel<<<BATCH / TB, 256, 0, stream>>>(
            x, p, f, b_in, bs0, bs1, bs2, bs3, b_out, wq, out);
    } else {
        fused_pdf_legacy<<<BATCH / TB, 256, 0, stream>>>(
            x, p, f, W_in, b_in, Ws0, bs0, Ws1, bs1, Ws2, bs2, Ws3, bs3, W_out, b_out, out);
    }
}

// Round 11
// 485.783 us; speedup vs baseline: 3.1297x; 1.1407x over previous
//
#include <hip/hip_runtime.h>
#include <math.h>

#define BATCH 65536
#define LEAD  24
#define MEM   51
#define NPRED 6
#define HID   128
#define TB    64
#define NBLK  4
#define OUTC  960

#define HSTR  136            // bf16 plane stride
#define HPL   (64 * HSTR)    // elements per plane
#define CSTR  165            // f32 C-stage stride (165≡5 mod 32 -> spline reads 2-way/free)

// prepped-weight layout in d_ws (ushort units), FRAGMENT-MAJOR within each region:
//   addr(tile,kk,lane,j) = ((tile*KT + kk)*64 + lane)*8 + j
//   element = W^T[tile*16 + (lane&15)][kk*32 + (lane>>4)*8 + j]
//   W_inT  hi [0,8192)        lo [8192,16384)        (8 tiles, KT=2, k>=54 zero)
//   WsT l  hi 16384+l*32768   lo +16384              (8 tiles, KT=4)
//   W_outT hi 147456          lo 270336              (60 tiles, KT=4)
#define WS_USHORTS 393216
#define WS_BYTES   786432

typedef float f32x4 __attribute__((ext_vector_type(4)));
typedef short s16x8 __attribute__((ext_vector_type(8)));

__device__ __forceinline__ float sp_softplus(float z) {
    return fmaxf(z, 0.0f) + log1pf(expf(-fabsf(z)));
}
__device__ __forceinline__ float silu_f(float z) {
    return z / (1.0f + expf(-z));
}
// x ~= hi + lo (bf16 each), dropped term <= 2^-16 rel
__device__ __forceinline__ void bf16split(float x, unsigned &hi, unsigned &lo) {
    unsigned xb = __float_as_uint(x);
    hi = xb >> 16;
    float fhi = __uint_as_float(xb & 0xFFFF0000u);
    lo = __float_as_uint(x - fhi) >> 16;
}
__device__ __forceinline__ float bf16re(short u) {
    return __uint_as_float(((unsigned)(unsigned short)u) << 16);
}

// ---------------- prep: transpose + hi/lo split into FRAGMENT-MAJOR order ----------------
__global__ __launch_bounds__(256) void prep_kernel(
    const float* __restrict__ W_in,
    const float* __restrict__ Ws0, const float* __restrict__ Ws1,
    const float* __restrict__ Ws2, const float* __restrict__ Ws3,
    const float* __restrict__ W_out, unsigned short* __restrict__ wq)
{
    int idx = blockIdx.x * 256 + threadIdx.x;   // 0..196607
    float val; int ih, il;
    if (idx < 8192) {                  // W_inT: tile(8) x kt(2) x lane(64) x j(8)
        int tile = idx >> 10, rem = idx & 1023;
        int kk = rem >> 9, lane = (rem >> 3) & 63, j = rem & 7;
        int col = tile * 16 + (lane & 15);
        int k   = kk * 32 + (lane >> 4) * 8 + j;
        val = (k < 54) ? W_in[k * HID + col] : 0.0f;
        ih = idx; il = 8192 + idx;
    } else if (idx < 73728) {          // WsT: 4 layers x tile(8) x kt(4) x lane x j
        int r = idx - 8192, l = r >> 14, r2 = r & 16383;
        int tile = r2 >> 11, rem = r2 & 2047;
        int kk = rem >> 9, lane = (rem >> 3) & 63, j = rem & 7;
        int col = tile * 16 + (lane & 15);
        int k   = kk * 32 + (lane >> 4) * 8 + j;
        const float* W = (l == 0) ? Ws0 : (l == 1) ? Ws1 : (l == 2) ? Ws2 : Ws3;
        val = W[k * HID + col];
        ih = 16384 + l * 32768 + r2; il = ih + 16384;
    } else {                           // W_outT: tile(60) x kt(4) x lane x j
        int r = idx - 73728;
        int tile = r >> 11, rem = r & 2047;
        int kk = rem >> 9, lane = (rem >> 3) & 63, j = rem & 7;
        int col = tile * 16 + (lane & 15);
        int k   = kk * 32 + (lane >> 4) * 8 + j;
        val = W_out[k * OUTC + col];
        ih = 147456 + r; il = 270336 + r;
    }
    unsigned hi, lo; bf16split(val, hi, lo);
    wq[ih] = (unsigned short)hi;
    wq[il] = (unsigned short)lo;
}

// ---------------- writeback: acc -> silu(+skip) -> split bf16 planes ----------------
template<bool SKIP>
__device__ __forceinline__ void writeback(f32x4 (&acc)[4][2], short* hpl,
                                          const float* __restrict__ bias,
                                          int w, int lL, int lH) {
    const bool evn = (lL & 1) == 0;
    unsigned* u32p = (unsigned*)hpl;
    #pragma unroll
    for (int n = 0; n < 2; ++n) {
        const int colb = w * 32 + n * 16 + lL;
        const float bv = bias[colb];
        #pragma unroll
        for (int m = 0; m < 4; ++m) {
            #pragma unroll
            for (int r = 0; r < 4; ++r) {
                const int row = m * 16 + lH * 4 + r;
                float v = acc[m][n][r] + bv;
                float hnew;
                if (SKIP) {
                    float ho = bf16re(hpl[row * HSTR + colb]) + bf16re(hpl[HPL + row * HSTR + colb]);
                    hnew = silu_f(v) + ho;   // ds_read precedes ds_write in program order: safe
                } else {
                    hnew = silu_f(v);
                }
                unsigned hi, lo; bf16split(hnew, hi, lo);
                unsigned phi = (unsigned)__shfl_xor((int)hi, 1);
                unsigned plo = (unsigned)__shfl_xor((int)lo, 1);
                if (evn) {   // even-col lane packs (col, col+1) -> one b32 per plane
                    u32p[(row * HSTR + colb) >> 1]       = hi | (phi << 16);
                    u32p[(HPL + row * HSTR + colb) >> 1] = lo | (plo << 16);
                }
            }
        }
    }
}

#define MFMA(a, b, c) __builtin_amdgcn_mfma_f32_16x16x32_bf16((a), (b), (c), 0, 0, 0)

// ---------------- main fused kernel (MFMA path) ----------------
__global__ __launch_bounds__(256, 2) void fused_mfma_kernel(
    const float* __restrict__ x, const float* __restrict__ p, const float* __restrict__ f,
    const float* __restrict__ b_in,
    const float* __restrict__ bs0, const float* __restrict__ bs1,
    const float* __restrict__ bs2, const float* __restrict__ bs3,
    const float* __restrict__ b_out,
    const unsigned short* __restrict__ wq,
    float* __restrict__ out)
{
    __shared__ short hpl[2 * HPL];        // 34816 B: activation hi/lo planes [64][HSTR]
    __shared__ float cbuf[64 * CSTR];     // 42240 B: out-layer C stage (4 leads = 160 cols)

    const int t    = threadIdx.x;
    const int lane = t & 63;
    const int w    = t >> 6;
    const int lL   = lane & 15;
    const int lH   = lane >> 4;
    const int b0   = blockIdx.x * TB;

    // -------- phase 0: stats -> split-bf16 input planes (cols 0..53, 54..63 zero) --------
    {
        const int grp = lane >> 4, sub = lane & 15;
        for (int it = 0; it < (TB * LEAD) / 16; ++it) {
            int rowl = it * 16 + w * 4 + grp;
            const float* xr = x + (size_t)(b0 * LEAD + rowl) * MEM;
            float v0 = xr[sub], v1 = xr[sub + 16], v2 = xr[sub + 32];
            float v3 = (sub < 3) ? xr[sub + 48] : 0.0f;
            float sum = v0 + v1 + v2 + v3;
            float ss  = v0 * v0 + v1 * v1 + v2 * v2 + v3 * v3;
            sum += __shfl_xor(sum, 1);  ss += __shfl_xor(ss, 1);
            sum += __shfl_xor(sum, 2);  ss += __shfl_xor(ss, 2);
            sum += __shfl_xor(sum, 4);  ss += __shfl_xor(ss, 4);
            sum += __shfl_xor(sum, 8);  ss += __shfl_xor(ss, 8);
            if (sub == 0) {
                int bl = rowl / LEAD, ld = rowl - bl * LEAD;
                float mv = sum / 51.0f;
                float sd = sqrtf(fmaxf((ss - 51.0f * mv * mv) / 50.0f, 0.0f));
                unsigned hi, lo;
                bf16split(mv, hi, lo);
                hpl[bl * HSTR + 2 * ld] = (short)hi;  hpl[HPL + bl * HSTR + 2 * ld] = (short)lo;
                bf16split(sd, hi, lo);
                hpl[bl * HSTR + 2 * ld + 1] = (short)hi;  hpl[HPL + bl * HSTR + 2 * ld + 1] = (short)lo;
            }
        }
        for (int idx = t; idx < TB * NPRED; idx += 256) {
            int bl = idx / NPRED, j = idx - bl * NPRED;
            unsigned hi, lo;
            bf16split(p[(size_t)(b0 + bl) * NPRED + j], hi, lo);
            hpl[bl * HSTR + 48 + j] = (short)hi;  hpl[HPL + bl * HSTR + 48 + j] = (short)lo;
        }
        {   // zero-pad cols 54..63
            int row = t >> 2;
            unsigned* u32p = (unsigned*)hpl;
            for (int c2 = 54 + 2 * (t & 3); c2 < 64; c2 += 8) {
                u32p[(row * HSTR + c2) >> 1] = 0u;
                u32p[(HPL + row * HSTR + c2) >> 1] = 0u;
            }
        }
    }
    __syncthreads();

    // -------- phase 1: input layer GEMM 64x128, K=64, 3-pass split --------
    {
        f32x4 acc[4][2];
        #pragma unroll
        for (int m = 0; m < 4; ++m)
            #pragma unroll
            for (int n = 0; n < 2; ++n) acc[m][n] = (f32x4){0.f, 0.f, 0.f, 0.f};
        #pragma unroll
        for (int n = 0; n < 2; ++n) {
            const int tile = w * 2 + n;
            #pragma unroll
            for (int kk = 0; kk < 2; ++kk) {
                const unsigned short* bp_ = wq + ((tile * 2 + kk) * 64 + lane) * 8;
                s16x8 bh = *(const s16x8*)bp_;
                s16x8 bl = *(const s16x8*)(bp_ + 8192);
                #pragma unroll
                for (int m = 0; m < 4; ++m) {
                    const short* ap = &hpl[(m * 16 + lL) * HSTR + kk * 32 + lH * 8];
                    s16x8 ah = *(const s16x8*)ap;
                    s16x8 al = *(const s16x8*)(ap + HPL);
                    acc[m][n] = MFMA(ah, bh, acc[m][n]);
                    acc[m][n] = MFMA(ah, bl, acc[m][n]);
                    acc[m][n] = MFMA(al, bh, acc[m][n]);
                }
            }
        }
        __syncthreads();
        writeback<false>(acc, hpl, b_in, w, lL, lH);
    }
    __syncthreads();

    // -------- phase 2: 4 skip layers, K=128 --------
    {
        const float* bsp[4] = {bs0, bs1, bs2, bs3};
        #pragma unroll 1
        for (int L = 0; L < 4; ++L) {
            const unsigned short* wsl = wq + 16384 + L * 32768;
            const float* bp = bsp[L];
            f32x4 acc[4][2];
            #pragma unroll
            for (int m = 0; m < 4; ++m)
                #pragma unroll
                for (int n = 0; n < 2; ++n) acc[m][n] = (f32x4){0.f, 0.f, 0.f, 0.f};
            #pragma unroll
            for (int n = 0; n < 2; ++n) {
                const int tile = w * 2 + n;
                #pragma unroll
                for (int kk = 0; kk < 4; ++kk) {
                    const unsigned short* bp_ = wsl + ((tile * 4 + kk) * 64 + lane) * 8;
                    s16x8 bh = *(const s16x8*)bp_;
                    s16x8 bl = *(const s16x8*)(bp_ + 16384);
                    #pragma unroll
                    for (int m = 0; m < 4; ++m) {
                        const short* ap = &hpl[(m * 16 + lL) * HSTR + kk * 32 + lH * 8];
                        s16x8 ah = *(const s16x8*)ap;
                        s16x8 al = *(const s16x8*)(ap + HPL);
                        acc[m][n] = MFMA(ah, bh, acc[m][n]);
                        acc[m][n] = MFMA(ah, bl, acc[m][n]);
                        acc[m][n] = MFMA(al, bh, acc[m][n]);
                    }
                }
            }
            __syncthreads();
            writeback<true>(acc, hpl, bp, w, lL, lH);
            __syncthreads();
        }
    }

    // -------- phase 3: out layer (4 leads/group, waves split M) + spline --------
    const unsigned short* wop = wq + 147456;
    #pragma unroll 1
    for (int g = 0; g < 6; ++g) {
        #pragma unroll 1
        for (int nt = 0; nt < 10; ++nt) {
            const int colg = g * 160 + nt * 16 + lL;
            f32x4 d = {0.f, 0.f, 0.f, 0.f};
            #pragma unroll
            for (int kk = 0; kk < 4; ++kk) {
                const unsigned short* bp_ = wop + (((g * 10 + nt) * 4 + kk) * 64 + lane) * 8;
                s16x8 bh = *(const s16x8*)bp_;
                s16x8 bl = *(const s16x8*)(bp_ + 122880);
                const short* ap = &hpl[(w * 16 + lL) * HSTR + kk * 32 + lH * 8];
                s16x8 ah = *(const s16x8*)ap;
                s16x8 al = *(const s16x8*)(ap + HPL);
                d = MFMA(ah, bh, d);
                d = MFMA(ah, bl, d);
                d = MFMA(al, bh, d);
            }
            const float bv = b_out[colg];
            #pragma unroll
            for (int r = 0; r < 4; ++r)
                cbuf[(w * 16 + lH * 4 + r) * CSTR + nt * 16 + lL] = d[r] + bv;
        }
        __syncthreads();

        {   // spline: thread -> (b = t&63, lead = g*4 + (t>>6))
            const int b = t & 63, l = t >> 6;
            const float* cc = &cbuf[b * CSTR + l * 40];
            float ff = f[(size_t)(b0 + b) * LEAD + g * 4 + l];
            float dt_prod = 1.0f;
            #pragma unroll
            for (int blk = 0; blk < NBLK; ++blk) {
                float tk[5], yk[5];
                tk[0] = cc[blk * 10 + 0];
                yk[0] = cc[blk * 10 + 5];
                #pragma unroll
                for (int kk = 1; kk < 5; ++kk) {
                    tk[kk] = tk[kk - 1] + 0.001f + sp_softplus(cc[blk * 10 + kk]);
                    yk[kk] = yk[kk - 1] + 0.001f + sp_softplus(cc[blk * 10 + 5 + kk]);
                }
                float df[4];
                #pragma unroll
                for (int j = 0; j < 4; ++j) df[j] = (yk[j + 1] - yk[j]) / (tk[j + 1] - tk[j]);
                float g02 = (yk[2] - yk[0]) / (tk[2] - tk[0]);
                float g13 = (yk[3] - yk[1]) / (tk[3] - tk[1]);
                float g24 = (yk[4] - yk[2]) / (tk[4] - tk[2]);
                float dd[5];
                dd[0] = df[0] * df[0] / g02;
                dd[1] = df[0] * df[1] / g02;
                dd[2] = df[1] * df[2] / g13;
                dd[3] = df[2] * df[3] / g24;
                dd[4] = df[3] * df[3] / g24;

                int cnt = (ff > tk[0]) + (ff > tk[1]) + (ff > tk[2]) + (ff > tk[3]) + (ff > tk[4]);
                bool e0 = (cnt == 0), e1 = (cnt == 5);
                int k0 = cnt - 1; k0 = k0 < 0 ? 0 : (k0 > 3 ? 3 : k0);

                float t0v = tk[0], t1v = tk[1], y0v = yk[0], y1v = yk[1], d0v = dd[0], d1v = dd[1];
                #pragma unroll
                for (int j = 1; j < 4; ++j) {
                    bool c = (k0 == j);
                    t0v = c ? tk[j] : t0v;  t1v = c ? tk[j + 1] : t1v;
                    y0v = c ? yk[j] : y0v;  y1v = c ? yk[j + 1] : y1v;
                    d0v = c ? dd[j] : d0v;  d1v = c ? dd[j + 1] : d1v;
                }

                float dt_ = t1v - t0v, dy_ = y1v - y0v;
                float s_  = dy_ / dt_;
                float e   = (ff - t0v) / dt_;
                float one_e = 1.0f - e;
                float bb  = d1v + d0v - 2.0f * s_;
                float n0  = dy_ * (s_ * e * e + d0v * e * one_e);
                float n1  = s_ + bb * e * one_e;
                float p_mid = y0v + n0 / n1;
                float p_lo  = d0v * ff + (y0v - d0v * t0v);
                float p_hi  = d1v * ff + (y1v - d1v * t1v);
                float val = e0 ? p_lo : (e1 ? p_hi : p_mid);

                float div0 = s_ * s_ * (d1v * e * e + 2.0f * s_ * e * one_e + d0v * one_e * one_e);
                float div1 = n1 * n1;
                float der  = e0 ? d0v : (e1 ? d1v : div0 / div1);

                dt_prod *= der;
                ff = val;
            }
            out[(size_t)(b0 + b) * LEAD + g * 4 + l] =
                expf(-0.5f * ff * ff) * dt_prod / 2.5066282746310002f;
        }
        __syncthreads();
    }
}

// ---------------- legacy fallback (round-2 kernel, used only if ws too small) ----------------
#define DIN 54
__global__ __launch_bounds__(256, 2) void fused_pdf_legacy(
    const float* __restrict__ x, const float* __restrict__ p, const float* __restrict__ f,
    const float* __restrict__ W_in, const float* __restrict__ b_in,
    const float* __restrict__ Ws0, const float* __restrict__ bs0,
    const float* __restrict__ Ws1, const float* __restrict__ bs1,
    const float* __restrict__ Ws2, const float* __restrict__ bs2,
    const float* __restrict__ Ws3, const float* __restrict__ bs3,
    const float* __restrict__ W_out, const float* __restrict__ b_out,
    float* __restrict__ out)
{
    __shared__ float s_in[DIN * TB];
    __shared__ float s_h[HID * TB];
    const int t = threadIdx.x, lane = t & 63, w = t >> 6;
    const int b0 = blockIdx.x * TB;
    {
        const int grp = lane >> 4, sub = lane & 15;
        for (int it = 0; it < (TB * LEAD) / 16; ++it) {
            int rowl = it * 16 + w * 4 + grp;
            const float* xr = x + (size_t)(b0 * LEAD + rowl) * MEM;
            float v0 = xr[sub], v1 = xr[sub + 16], v2 = xr[sub + 32];
            float v3 = (sub < 3) ? xr[sub + 48] : 0.0f;
            float sum = v0 + v1 + v2 + v3;
            float ss  = v0 * v0 + v1 * v1 + v2 * v2 + v3 * v3;
            sum += __shfl_xor(sum, 1);  ss += __shfl_xor(ss, 1);
            sum += __shfl_xor(sum, 2);  ss += __shfl_xor(ss, 2);
            sum += __shfl_xor(sum, 4);  ss += __shfl_xor(ss, 4);
            sum += __shfl_xor(sum, 8);  ss += __shfl_xor(ss, 8);
            if (sub == 0) {
                int bl = rowl / LEAD, ld = rowl - bl * LEAD;
                float m = sum / 51.0f;
                float var = (ss - 51.0f * m * m) / 50.0f;
                s_in[(2 * ld) * TB + bl] = m;
                s_in[(2 * ld + 1) * TB + bl] = sqrtf(fmaxf(var, 0.0f));
            }
        }
        for (int idx = t; idx < TB * NPRED; idx += 256) {
            int bl = idx / NPRED, j = idx - bl * NPRED;
            s_in[(2 * LEAD + j) * TB + bl] = p[(size_t)(b0 + bl) * NPRED + j];
        }
    }
    __syncthreads();
    const int j0 = __builtin_amdgcn_readfirstlane(w * 32);
    float hreg[32];
    {
        float acc[32];
        #pragma unroll
        for (int jj = 0; jj < 32; ++jj) acc[jj] = 0.0f;
        for (int k = 0; k < DIN; ++k) {
            float a = s_in[k * TB + lane];
            const float* wr = W_in + k * HID + j0;
            #pragma unroll
            for (int jj = 0; jj < 32; ++jj) acc[jj] = fmaf(a, wr[jj], acc[jj]);
        }
        #pragma unroll
        for (int jj = 0; jj < 32; ++jj) {
            hreg[jj] = silu_f(acc[jj] + b_in[j0 + jj]);
            s_h[(j0 + jj) * TB + lane] = hreg[jj];
        }
    }
    __syncthreads();
    const float* Wl[4] = {Ws0, Ws1, Ws2, Ws3};
    const float* Bl[4] = {bs0, bs1, bs2, bs3};
    #pragma unroll
    for (int L = 0; L < 4; ++L) {
        const float* Wp = Wl[L];
        const float* bp = Bl[L];
        float acc[32];
        #pragma unroll
        for (int jj = 0; jj < 32; ++jj) acc[jj] = 0.0f;
        for (int k = 0; k < HID; ++k) {
            float a = s_h[k * TB + lane];
            const float* wr = Wp + k * HID + j0;
            #pragma unroll
            for (int jj = 0; jj < 32; ++jj) acc[jj] = fmaf(a, wr[jj], acc[jj]);
        }
        __syncthreads();
        #pragma unroll
        for (int jj = 0; jj < 32; ++jj) {
            hreg[jj] = silu_f(acc[jj] + bp[j0 + jj]) + hreg[jj];
            s_h[(j0 + jj) * TB + lane] = hreg[jj];
        }
        __syncthreads();
    }
    for (int q = 0; q < LEAD / 4; ++q) {
        const int lead = __builtin_amdgcn_readfirstlane(q * 4 + w);
        const int base = lead * 40;
        float acc[40];
        #pragma unroll
        for (int c = 0; c < 40; ++c) acc[c] = 0.0f;
        for (int k = 0; k < HID; ++k) {
            float a = s_h[k * TB + lane];
            const float* wr = W_out + k * OUTC + base;
            #pragma unroll
            for (int c = 0; c < 40; ++c) acc[c] = fmaf(a, wr[c], acc[c]);
        }
        #pragma unroll
        for (int c = 0; c < 40; ++c) acc[c] += b_out[base + c];
        float ff = f[(size_t)(b0 + lane) * LEAD + lead];
        float dt_prod = 1.0f;
        #pragma unroll
        for (int blk = 0; blk < NBLK; ++blk) {
            float tk[5], yk[5];
            tk[0] = acc[blk * 10 + 0];
            yk[0] = acc[blk * 10 + 5];
            #pragma unroll
            for (int kk = 1; kk < 5; ++kk) {
                tk[kk] = tk[kk - 1] + 0.001f + sp_softplus(acc[blk * 10 + kk]);
                yk[kk] = yk[kk - 1] + 0.001f + sp_softplus(acc[blk * 10 + 5 + kk]);
            }
            float df[4];
            #pragma unroll
            for (int j = 0; j < 4; ++j) df[j] = (yk[j + 1] - yk[j]) / (tk[j + 1] - tk[j]);
            float g02 = (yk[2] - yk[0]) / (tk[2] - tk[0]);
            float g13 = (yk[3] - yk[1]) / (tk[3] - tk[1]);
            float g24 = (yk[4] - yk[2]) / (tk[4] - tk[2]);
            float dd[5];
            dd[0] = df[0] * df[0] / g02;
            dd[1] = df[0] * df[1] / g02;
            dd[2] = df[1] * df[2] / g13;
            dd[3] = df[2] * df[3] / g24;
            dd[4] = df[3] * df[3] / g24;
            int cnt = (ff > tk[0]) + (ff > tk[1]) + (ff > tk[2]) + (ff > tk[3]) + (ff > tk[4]);
            bool e0 = (cnt == 0), e1 = (cnt == 5);
            int k0 = cnt - 1; k0 = k0 < 0 ? 0 : (k0 > 3 ? 3 : k0);
            float t0v = tk[0], t1v = tk[1], y0v = yk[0], y1v = yk[1], d0v = dd[0], d1v = dd[1];
            #pragma unroll
            for (int j = 1; j < 4; ++j) {
                bool c = (k0 == j);
                t0v = c ? tk[j] : t0v;  t1v = c ? tk[j + 1] : t1v;
                y0v = c ? yk[j] : y0v;  y1v = c ? yk[j + 1] : y1v;
                d0v = c ? dd[j] : d0v;  d1v = c ? dd[j + 1] : d1v;
            }
            float dt_ = t1v - t0v, dy_ = y1v - y0v;
            float s_  = dy_ / dt_;
            float e   = (ff - t0v) / dt_;
            float one_e = 1.0f - e;
            float bb  = d1v + d0v - 2.0f * s_;
            float n0  = dy_ * (s_ * e * e + d0v * e * one_e);
            float n1  = s_ + bb * e * one_e;
            float p_mid = y0v + n0 / n1;
            float p_lo  = d0v * ff + (y0v - d0v * t0v);
            float p_hi  = d1v * ff + (y1v - d1v * t1v);
            float val = e0 ? p_lo : (e1 ? p_hi : p_mid);
            float div0 = s_ * s_ * (d1v * e * e + 2.0f * s_ * e * one_e + d0v * one_e * one_e);
            float div1 = n1 * n1;
            float der  = e0 ? d0v : (e1 ? d1v : div0 / div1);
            dt_prod *= der;
            ff = val;
        }
        out[(size_t)(b0 + lane) * LEAD + lead] =
            expf(-0.5f * ff * ff) * dt_prod / 2.5066282746310002f;
    }
}

extern "C" void kernel_launch(void* const* d_in, const int* in_sizes, int n_in,
                              void* d_out, int out_size, void* d_ws, size_t ws_size,
                              hipStream_t stream) {
    const float* x     = (const float*)d_in[0];
    const float* p     = (const float*)d_in[1];
    const float* f     = (const float*)d_in[2];
    const float* W_in  = (const float*)d_in[3];
    const float* b_in  = (const float*)d_in[4];
    const float* Ws0   = (const float*)d_in[5];
    const float* bs0   = (const float*)d_in[6];
    const float* Ws1   = (const float*)d_in[7];
    const float* bs1   = (const float*)d_in[8];
    const float* Ws2   = (const float*)d_in[9];
    const float* bs2   = (const float*)d_in[10];
    const float* Ws3   = (const float*)d_in[11];
    const float* bs3   = (const float*)d_in[12];
    const float* W_out = (const float*)d_in[13];
    const float* b_out = (const float*)d_in[14];
    float* out = (float*)d_out;

    if (ws_size >= (size_t)WS_BYTES) {
        unsigned short* wq = (unsigned short*)d_ws;
        prep_kernel<<<768, 256, 0, stream>>>(W_in, Ws0, Ws1, Ws2, Ws3, W_out, wq);
        fused_mfma_kernel<<<BATCH / TB, 256, 0, stream>>>(
            x, p, f, b_in, bs0, bs1, bs2, bs3, b_out, wq, out);
    } else {
        fused_pdf_legacy<<<BATCH / TB, 256, 0, stream>>>(
            x, p, f, W_in, b_in, Ws0, bs0, Ws1, bs1, Ws2, bs2, Ws3, bs3, W_out, b_out, out);
    }
}